// Round 5
// baseline (18814.789 us; speedup 1.0000x reference)
//
#include <hip/hip_runtime.h>

// Problem constants (from reference)
#define SEQ   8192
#define HID   256
#define G3    768      // 3*HID
#define TSTART 1024    // SEQ/8
#define NEGD  1365     // SEQ/6
#define TCNT  5791     // (SEQ - 10 - NEGD - 4 + 2) - TSTART
#define DENOMF 23164.0f // TCNT*4

typedef _Float16 half2_t __attribute__((ext_vector_type(2)));

__device__ __forceinline__ float fdot2(half2_t a, half2_t b, float c) {
#if __has_builtin(__builtin_amdgcn_fdot2)
  return __builtin_amdgcn_fdot2(a, b, c, false);
#else
  return c + (float)a.x * (float)b.x + (float)a.y * (float)b.y;
#endif
}

__device__ __forceinline__ half2_t h2_from_u32(unsigned int u) {
  return __builtin_bit_cast(half2_t, u);
}

__device__ __forceinline__ float sigmoidf_fast(float x) {
  return 1.0f / (1.0f + __expf(-x));
}
// tanh via sigmoid form: safe at both extremes (exp under/overflow -> +-1)
__device__ __forceinline__ float tanhf_fast(float x) {
  return 2.0f / (1.0f + __expf(-2.0f * x)) - 1.0f;
}

// ---------------------------------------------------------------------------
// init: zero the loss accumulators (ws is poisoned 0xAA every call)
// ---------------------------------------------------------------------------
__global__ void init_kernel(float* accum) {
  if (threadIdx.x < 2) accum[threadIdx.x] = 0.0f;
}

// ---------------------------------------------------------------------------
// Phase A: xW = data @ Wih^T + bih -> f32 [SEQ][768]. All f32.
// grid (256, 3), block 256. Thread owns output col o; 32-row x-tile in LDS.
// ---------------------------------------------------------------------------
__global__ __launch_bounds__(256) void xw_kernel(
    const float* __restrict__ data, const float* __restrict__ Wih,
    const float* __restrict__ bih, float* __restrict__ xw)
{
  __shared__ float4 xs4[32 * 64];   // 32 rows x 256 f32 = 32 KB
  const int o  = blockIdx.y * 256 + threadIdx.x;
  const int m0 = blockIdx.x * 32;

  float* xsf = (float*)xs4;
  for (int r = 0; r < 32; ++r)
    xsf[r * 256 + threadIdx.x] = data[(size_t)(m0 + r) * 256 + threadIdx.x];
  __syncthreads();

  const float b = bih[o];
  float acc[32];
#pragma unroll
  for (int r = 0; r < 32; ++r) acc[r] = b;

  const float4* wrow = (const float4*)(Wih + (size_t)o * 256);
  for (int kc = 0; kc < 4; ++kc) {
    float4 w[16];
#pragma unroll
    for (int j = 0; j < 16; ++j) w[j] = wrow[kc * 16 + j];
#pragma unroll
    for (int r = 0; r < 32; ++r) {
      const float4* xr = xs4 + r * 64 + kc * 16;
      float a0 = 0.f, a1 = 0.f, a2 = 0.f, a3 = 0.f;
#pragma unroll
      for (int j = 0; j < 4; ++j) {
        float4 x0 = xr[4 * j + 0], x1 = xr[4 * j + 1];
        float4 x2 = xr[4 * j + 2], x3 = xr[4 * j + 3];
        float4 w0 = w[4 * j + 0], w1 = w[4 * j + 1];
        float4 w2 = w[4 * j + 2], w3 = w[4 * j + 3];
        a0 = fmaf(w0.x, x0.x, fmaf(w0.y, x0.y, fmaf(w0.z, x0.z, fmaf(w0.w, x0.w, a0))));
        a1 = fmaf(w1.x, x1.x, fmaf(w1.y, x1.y, fmaf(w1.z, x1.z, fmaf(w1.w, x1.w, a1))));
        a2 = fmaf(w2.x, x2.x, fmaf(w2.y, x2.y, fmaf(w2.z, x2.z, fmaf(w2.w, x2.w, a2))));
        a3 = fmaf(w3.x, x3.x, fmaf(w3.y, x3.y, fmaf(w3.z, x3.z, fmaf(w3.w, x3.w, a3))));
      }
      acc[r] += (a0 + a1) + (a2 + a3);
    }
  }
  for (int r = 0; r < 32; ++r)
    xw[(size_t)(m0 + r) * G3 + o] = acc[r];
}

// ---------------------------------------------------------------------------
// data row norms: one wave per row (f32 data)
// ---------------------------------------------------------------------------
__global__ __launch_bounds__(256) void rnorm_kernel(
    const float* __restrict__ data, float* __restrict__ rn)
{
  int wave = threadIdx.x >> 6, lane = threadIdx.x & 63;
  int row = blockIdx.x * 4 + wave;
  const float* xr = data + (size_t)row * HID;
  float a = xr[lane], b = xr[lane + 64], c = xr[lane + 128], d = xr[lane + 192];
  float s = a * a + b * b + c * c + d * d;
#pragma unroll
  for (int off = 32; off; off >>= 1) s += __shfl_xor(s, off, 64);
  if (lane == 0) rn[row] = fmaxf(sqrtf(s), 1e-8f);
}

// ---------------------------------------------------------------------------
// Phase B: sequential GRU scan. ONE block, 256 threads (4 waves, 1/SIMD,
// 512-VGPR budget). Thread i owns ALL THREE gate rows (r_i, z_i, n_i) of
// Whh as 384 f16x2 VGPRs, so the gate math is thread-local: no gh/xn/hf
// LDS round-trip, ONE barrier per step. h is double-buffered in LDS as
// packed f16 (wave-uniform broadcast reads, depth-6 prefetch ring).
// ---------------------------------------------------------------------------
__global__ __launch_bounds__(256, 1) void gru_kernel(
    const float* __restrict__ Whh, const float* __restrict__ bhh,
    const float* __restrict__ xw, float* __restrict__ zout)
{
  __shared__ uint4 hb[2][32];    // double-buffered h: 256 packed f16 each
  const int i = threadIdx.x;

  // --- load the 3 gate rows for column i into f16x2 registers ---
  half2_t wr[128], wz[128], wn[128];
  {
    const float4* pr = (const float4*)(Whh + (size_t)i * 256);
    const float4* pz = (const float4*)(Whh + (size_t)(256 + i) * 256);
    const float4* pn = (const float4*)(Whh + (size_t)(512 + i) * 256);
#pragma unroll
    for (int j = 0; j < 64; ++j) {
      float4 a = pr[j];
      half2_t p0; p0.x = (_Float16)a.x; p0.y = (_Float16)a.y;
      half2_t p1; p1.x = (_Float16)a.z; p1.y = (_Float16)a.w;
      wr[2 * j] = p0; wr[2 * j + 1] = p1;
    }
#pragma unroll
    for (int j = 0; j < 64; ++j) {
      float4 a = pz[j];
      half2_t p0; p0.x = (_Float16)a.x; p0.y = (_Float16)a.y;
      half2_t p1; p1.x = (_Float16)a.z; p1.y = (_Float16)a.w;
      wz[2 * j] = p0; wz[2 * j + 1] = p1;
    }
#pragma unroll
    for (int j = 0; j < 64; ++j) {
      float4 a = pn[j];
      half2_t p0; p0.x = (_Float16)a.x; p0.y = (_Float16)a.y;
      half2_t p1; p1.x = (_Float16)a.z; p1.y = (_Float16)a.w;
      wn[2 * j] = p0; wn[2 * j + 1] = p1;
    }
  }
  const float br = bhh[i], bz = bhh[256 + i], bn = bhh[512 + i];

  if (i < 32) hb[0][i] = make_uint4(0u, 0u, 0u, 0u);
  __syncthreads();

  float hreg = 0.0f;
  // xW: current step's values + prefetch regs for the next step
  float xr0 = xw[i], xz0 = xw[256 + i], xn0 = xw[512 + i];

  for (int s = 0; s < SEQ; ++s) {
    // issue next step's xW loads now (HBM latency hidden behind the dot)
    const size_t bnext = (size_t)(s + 1 < SEQ ? s + 1 : s) * G3;
    float xr1 = xw[bnext + i], xz1 = xw[bnext + 256 + i], xn1 = xw[bnext + 512 + i];

    // --- 3 row-dots against h (LDS broadcast, depth-6 prefetch ring) ---
    const uint4* hrow = hb[s & 1];
    uint4 q[6];
#pragma unroll
    for (int p = 0; p < 6; ++p) q[p] = hrow[p];

    float ar0 = br, ar1 = 0.f, ar2 = 0.f, ar3 = 0.f;
    float az0 = bz, az1 = 0.f, az2 = 0.f, az3 = 0.f;
    float an0 = bn, an1 = 0.f, an2 = 0.f, an3 = 0.f;
#pragma unroll
    for (int j = 0; j < 32; ++j) {
      uint4 cur = q[j % 6];
      if (j + 6 < 32) q[j % 6] = hrow[j + 6];
      half2_t hx = h2_from_u32(cur.x), hy = h2_from_u32(cur.y);
      half2_t hz = h2_from_u32(cur.z), hw = h2_from_u32(cur.w);
      ar0 = fdot2(wr[4 * j + 0], hx, ar0);
      ar1 = fdot2(wr[4 * j + 1], hy, ar1);
      ar2 = fdot2(wr[4 * j + 2], hz, ar2);
      ar3 = fdot2(wr[4 * j + 3], hw, ar3);
      az0 = fdot2(wz[4 * j + 0], hx, az0);
      az1 = fdot2(wz[4 * j + 1], hy, az1);
      az2 = fdot2(wz[4 * j + 2], hz, az2);
      az3 = fdot2(wz[4 * j + 3], hw, az3);
      an0 = fdot2(wn[4 * j + 0], hx, an0);
      an1 = fdot2(wn[4 * j + 1], hy, an1);
      an2 = fdot2(wn[4 * j + 2], hz, an2);
      an3 = fdot2(wn[4 * j + 3], hw, an3);
    }

    // --- thread-local gate math (bias folded into acc init; n-bias inside r*) ---
    float rg = sigmoidf_fast(((ar0 + ar1) + (ar2 + ar3)) + xr0);
    float zg = sigmoidf_fast(((az0 + az1) + (az2 + az3)) + xz0);
    float ng = tanhf_fast(xn0 + rg * ((an0 + an1) + (an2 + an3)));
    hreg = (1.0f - zg) * ng + zg * hreg;

    zout[(size_t)s * HID + i] = hreg;                 // f32 z output
    ((_Float16*)hb[(s + 1) & 1])[i] = (_Float16)hreg; // h for next step
    __syncthreads();                                  // one barrier per step

    xr0 = xr1; xz0 = xz1; xn0 = xn1;
  }
}

// ---------------------------------------------------------------------------
// Phase C: NCE loss + accuracy. One block per t, 4 waves = 4 timespans.
// Reads f32 z straight from d_out.
// ---------------------------------------------------------------------------
__global__ __launch_bounds__(256) void cpc_kernel(
    const float* __restrict__ x, const float* __restrict__ zf,
    const float* __restrict__ rn, float* __restrict__ accum)
{
  __shared__ float zsh[HID];
  __shared__ float wsum[4];
  __shared__ float nce_s[4], acc_s[4];
  const int tt = TSTART + blockIdx.x;
  const int i = threadIdx.x;
  const int wave = i >> 6, lane = i & 63;

  float zi = zf[(size_t)tt * HID + i];
  zsh[i] = zi;
  float p = zi * zi;
#pragma unroll
  for (int off = 32; off; off >>= 1) p += __shfl_xor(p, off, 64);
  if (lane == 0) wsum[wave] = p;
  __syncthreads();
  float zn = fmaxf(sqrtf(wsum[0] + wsum[1] + wsum[2] + wsum[3]), 1e-8f);

  float z0 = zsh[lane], z1 = zsh[lane + 64], z2 = zsh[lane + 128], z3 = zsh[lane + 192];
  const int base = tt + wave + 1;   // pos index for timespan (wave+1)

  float tot[10];
#pragma unroll
  for (int n = 0; n < 10; ++n) {
    int idx = base + (n > 0 ? (NEGD + n - 1) : 0);
    const float* xr = x + (size_t)idx * HID;
    float q = xr[lane] * z0 + xr[lane + 64] * z1 + xr[lane + 128] * z2 + xr[lane + 192] * z3;
#pragma unroll
    for (int off = 32; off; off >>= 1) q += __shfl_xor(q, off, 64);
    tot[n] = q / (rn[idx] * zn);
  }
  float m = tot[0];
#pragma unroll
  for (int n = 1; n < 10; ++n) m = fmaxf(m, tot[n]);
  float se = 0.f;
#pragma unroll
  for (int n = 0; n < 10; ++n) se += expf(tot[n] - m);
  float logp0 = (tot[0] - m) - logf(se);
  float accv = (tot[0] >= m) ? 1.0f : 0.0f;  // argmax==0 iff tot[0] is the max

  if (lane == 0) { nce_s[wave] = -logp0; acc_s[wave] = accv; }
  __syncthreads();
  if (i == 0) {
    atomicAdd(accum,     nce_s[0] + nce_s[1] + nce_s[2] + nce_s[3]);
    atomicAdd(accum + 1, acc_s[0] + acc_s[1] + acc_s[2] + acc_s[3]);
  }
}

__global__ void fin_kernel(const float* __restrict__ accum,
                           float* __restrict__ out)
{
  if (threadIdx.x == 0) {
    out[(size_t)SEQ * HID]     = accum[0] / DENOMF;   // nce
    out[(size_t)SEQ * HID + 1] = accum[1] / DENOMF;   // acc
  }
}

// ---------------------------------------------------------------------------
extern "C" void kernel_launch(void* const* d_in, const int* in_sizes, int n_in,
                              void* d_out, int out_size, void* d_ws, size_t ws_size,
                              hipStream_t stream)
{
  // Inputs are f32 (reference dtypes). Output f32: z [SEQ*HID] | nce | acc.
  const float* data = (const float*)d_in[0];
  const float* Wih  = (const float*)d_in[1];
  const float* Whh  = (const float*)d_in[2];
  const float* bih  = (const float*)d_in[3];
  const float* bhh  = (const float*)d_in[4];
  float* out = (float*)d_out;

  // ws layout: xw f32 [SEQ*768] 25.17MB | rn f32 [SEQ] | accum f32 [2]
  char* p = (char*)d_ws;
  float* xw    = (float*)p;  p += (size_t)SEQ * G3 * sizeof(float);
  float* rn    = (float*)p;  p += (size_t)SEQ * sizeof(float);
  float* accum = (float*)p;

  init_kernel<<<1, 64, 0, stream>>>(accum);
  xw_kernel<<<dim3(256, 3), 256, 0, stream>>>(data, Wih, bih, xw);
  rnorm_kernel<<<SEQ / 4, 256, 0, stream>>>(data, rn);
  gru_kernel<<<1, 256, 0, stream>>>(Whh, bhh, xw, out);
  cpc_kernel<<<TCNT, 256, 0, stream>>>(data, out, rn, accum);
  fin_kernel<<<1, 1, 0, stream>>>(accum, out);
}

// Round 6
// 10083.096 us; speedup vs baseline: 1.8660x; 1.8660x over previous
//
#include <hip/hip_runtime.h>

// Problem constants (from reference)
#define SEQ   8192
#define HID   256
#define G3    768      // 3*HID
#define TSTART 1024    // SEQ/8
#define NEGD  1365     // SEQ/6
#define TCNT  5791     // (SEQ - 10 - NEGD - 4 + 2) - TSTART
#define DENOMF 23164.0f // TCNT*4

typedef _Float16 half2_t __attribute__((ext_vector_type(2)));

__device__ __forceinline__ float fdot2(half2_t a, half2_t b, float c) {
#if __has_builtin(__builtin_amdgcn_fdot2)
  return __builtin_amdgcn_fdot2(a, b, c, false);
#else
  return c + (float)a.x * (float)b.x + (float)a.y * (float)b.y;
#endif
}

__device__ __forceinline__ half2_t h2_from_u32(unsigned int u) {
  return __builtin_bit_cast(half2_t, u);
}

__device__ __forceinline__ float sigmoidf_fast(float x) {
  return 1.0f / (1.0f + __expf(-x));
}
// tanh via sigmoid form: safe at both extremes (exp under/overflow -> +-1)
__device__ __forceinline__ float tanhf_fast(float x) {
  return 2.0f / (1.0f + __expf(-2.0f * x)) - 1.0f;
}

// ---------------------------------------------------------------------------
// init: zero the loss accumulators (ws is poisoned 0xAA every call)
// ---------------------------------------------------------------------------
__global__ void init_kernel(float* accum) {
  if (threadIdx.x < 2) accum[threadIdx.x] = 0.0f;
}

// ---------------------------------------------------------------------------
// Phase A: xW = data @ Wih^T + bih -> f32 [SEQ][768]. All f32.
// grid (256, 3), block 256. Thread owns output col o; 32-row x-tile in LDS.
// ---------------------------------------------------------------------------
__global__ __launch_bounds__(256) void xw_kernel(
    const float* __restrict__ data, const float* __restrict__ Wih,
    const float* __restrict__ bih, float* __restrict__ xw)
{
  __shared__ float4 xs4[32 * 64];   // 32 rows x 256 f32 = 32 KB
  const int o  = blockIdx.y * 256 + threadIdx.x;
  const int m0 = blockIdx.x * 32;

  float* xsf = (float*)xs4;
  for (int r = 0; r < 32; ++r)
    xsf[r * 256 + threadIdx.x] = data[(size_t)(m0 + r) * 256 + threadIdx.x];
  __syncthreads();

  const float b = bih[o];
  float acc[32];
#pragma unroll
  for (int r = 0; r < 32; ++r) acc[r] = b;

  const float4* wrow = (const float4*)(Wih + (size_t)o * 256);
  for (int kc = 0; kc < 4; ++kc) {
    float4 w[16];
#pragma unroll
    for (int j = 0; j < 16; ++j) w[j] = wrow[kc * 16 + j];
#pragma unroll
    for (int r = 0; r < 32; ++r) {
      const float4* xr = xs4 + r * 64 + kc * 16;
      float a0 = 0.f, a1 = 0.f, a2 = 0.f, a3 = 0.f;
#pragma unroll
      for (int j = 0; j < 4; ++j) {
        float4 x0 = xr[4 * j + 0], x1 = xr[4 * j + 1];
        float4 x2 = xr[4 * j + 2], x3 = xr[4 * j + 3];
        float4 w0 = w[4 * j + 0], w1 = w[4 * j + 1];
        float4 w2 = w[4 * j + 2], w3 = w[4 * j + 3];
        a0 = fmaf(w0.x, x0.x, fmaf(w0.y, x0.y, fmaf(w0.z, x0.z, fmaf(w0.w, x0.w, a0))));
        a1 = fmaf(w1.x, x1.x, fmaf(w1.y, x1.y, fmaf(w1.z, x1.z, fmaf(w1.w, x1.w, a1))));
        a2 = fmaf(w2.x, x2.x, fmaf(w2.y, x2.y, fmaf(w2.z, x2.z, fmaf(w2.w, x2.w, a2))));
        a3 = fmaf(w3.x, x3.x, fmaf(w3.y, x3.y, fmaf(w3.z, x3.z, fmaf(w3.w, x3.w, a3))));
      }
      acc[r] += (a0 + a1) + (a2 + a3);
    }
  }
  for (int r = 0; r < 32; ++r)
    xw[(size_t)(m0 + r) * G3 + o] = acc[r];
}

// ---------------------------------------------------------------------------
// data row norms: one wave per row (f32 data)
// ---------------------------------------------------------------------------
__global__ __launch_bounds__(256) void rnorm_kernel(
    const float* __restrict__ data, float* __restrict__ rn)
{
  int wave = threadIdx.x >> 6, lane = threadIdx.x & 63;
  int row = blockIdx.x * 4 + wave;
  const float* xr = data + (size_t)row * HID;
  float a = xr[lane], b = xr[lane + 64], c = xr[lane + 128], d = xr[lane + 192];
  float s = a * a + b * b + c * c + d * d;
#pragma unroll
  for (int off = 32; off; off >>= 1) s += __shfl_xor(s, off, 64);
  if (lane == 0) rn[row] = fmaxf(sqrtf(s), 1e-8f);
}

// ---------------------------------------------------------------------------
// Phase B: sequential GRU scan. ONE block, 512 threads (8 waves, 2/SIMD,
// 256-VGPR budget). Thread (c,hf) [c=i&255, hf=i>>8] owns the hf-half
// (128 elements) of all three gate rows {c, 256+c, 512+c} as 192 f16x2
// VGPRs -- fits the 256-reg hard cap (round 5's 384-reg layout spilled:
// VGPR_Count==256 cap + scratch reloads = 2x regression). Half-partials
// exchanged through LDS; gate math thread-local (computed redundantly by
// both halves); h double-buffered in LDS as packed f16.
// ---------------------------------------------------------------------------
__global__ __launch_bounds__(512, 2) void gru_kernel(
    const float* __restrict__ Whh, const float* __restrict__ bhh,
    const float* __restrict__ xw, float* __restrict__ zout)
{
  __shared__ uint4 hb[2][32];      // double-buffered h: 256 packed f16 each
  __shared__ float par[3 * 512];   // [gate][hf][c] half-partials
  const int i  = threadIdx.x;
  const int c  = i & 255, hf = i >> 8;

  // --- load this thread's half of the 3 gate rows into f16x2 registers ---
  half2_t wr[64], wz[64], wn[64];
  {
    const float4* pr = (const float4*)(Whh + (size_t)c * 256 + hf * 128);
    const float4* pz = (const float4*)(Whh + (size_t)(256 + c) * 256 + hf * 128);
    const float4* pn = (const float4*)(Whh + (size_t)(512 + c) * 256 + hf * 128);
#pragma unroll
    for (int j = 0; j < 32; ++j) {
      float4 a = pr[j];
      half2_t p0; p0.x = (_Float16)a.x; p0.y = (_Float16)a.y;
      half2_t p1; p1.x = (_Float16)a.z; p1.y = (_Float16)a.w;
      wr[2 * j] = p0; wr[2 * j + 1] = p1;
    }
#pragma unroll
    for (int j = 0; j < 32; ++j) {
      float4 a = pz[j];
      half2_t p0; p0.x = (_Float16)a.x; p0.y = (_Float16)a.y;
      half2_t p1; p1.x = (_Float16)a.z; p1.y = (_Float16)a.w;
      wz[2 * j] = p0; wz[2 * j + 1] = p1;
    }
#pragma unroll
    for (int j = 0; j < 32; ++j) {
      float4 a = pn[j];
      half2_t p0; p0.x = (_Float16)a.x; p0.y = (_Float16)a.y;
      half2_t p1; p1.x = (_Float16)a.z; p1.y = (_Float16)a.w;
      wn[2 * j] = p0; wn[2 * j + 1] = p1;
    }
  }
  const float br = bhh[c], bz = bhh[256 + c], bn = bhh[512 + c];

  if (i < 32) hb[0][i] = make_uint4(0u, 0u, 0u, 0u);
  __syncthreads();

  float hreg = 0.0f;   // h[c], tracked redundantly by both hf copies
  float xr0 = xw[c], xz0 = xw[256 + c], xn0 = xw[512 + c];

  for (int s = 0; s < SEQ; ++s) {
    // issue next step's xW loads now (HBM/L2 latency hidden behind the dot)
    const size_t bnext = (size_t)(s + 1 < SEQ ? s + 1 : s) * G3;
    float xr1 = xw[bnext + c], xz1 = xw[bnext + 256 + c], xn1 = xw[bnext + 512 + c];

    // --- 3 half-row dots against this thread's half of h (LDS broadcast) ---
    const uint4* hrow = hb[s & 1] + hf * 16;
    uint4 q[4];
#pragma unroll
    for (int p = 0; p < 4; ++p) q[p] = hrow[p];

    float ar0 = 0.f, ar1 = 0.f, az0 = 0.f, az1 = 0.f, an0 = 0.f, an1 = 0.f;
#pragma unroll
    for (int j = 0; j < 16; ++j) {
      uint4 cur = q[j & 3];
      if (j + 4 < 16) q[j & 3] = hrow[j + 4];
      half2_t hx = h2_from_u32(cur.x), hy = h2_from_u32(cur.y);
      half2_t hz = h2_from_u32(cur.z), hw = h2_from_u32(cur.w);
      ar0 = fdot2(wr[4 * j + 0], hx, ar0);
      ar1 = fdot2(wr[4 * j + 1], hy, ar1);
      ar0 = fdot2(wr[4 * j + 2], hz, ar0);
      ar1 = fdot2(wr[4 * j + 3], hw, ar1);
      az0 = fdot2(wz[4 * j + 0], hx, az0);
      az1 = fdot2(wz[4 * j + 1], hy, az1);
      az0 = fdot2(wz[4 * j + 2], hz, az0);
      az1 = fdot2(wz[4 * j + 3], hw, az1);
      an0 = fdot2(wn[4 * j + 0], hx, an0);
      an1 = fdot2(wn[4 * j + 1], hy, an1);
      an0 = fdot2(wn[4 * j + 2], hz, an0);
      an1 = fdot2(wn[4 * j + 3], hw, an1);
    }

    // --- publish half-partials ([gate][hf][c]: conflict-free writes) ---
    par[0 * 512 + hf * 256 + c] = ar0 + ar1;
    par[1 * 512 + hf * 256 + c] = az0 + az1;
    par[2 * 512 + hf * 256 + c] = an0 + an1;
    __syncthreads();

    // --- gate math, redundantly in both halves (no divergence) ---
    float pr_ = par[0 * 512 + c] + par[0 * 512 + 256 + c];
    float pz_ = par[1 * 512 + c] + par[1 * 512 + 256 + c];
    float pn_ = par[2 * 512 + c] + par[2 * 512 + 256 + c];
    float rg = sigmoidf_fast(pr_ + br + xr0);
    float zg = sigmoidf_fast(pz_ + bz + xz0);
    float ng = tanhf_fast(xn0 + rg * (pn_ + bn));
    hreg = (1.0f - zg) * ng + zg * hreg;

    if (i < 256) {   // hf==0 copy publishes (waves 0-3: uniform branch)
      ((_Float16*)hb[(s + 1) & 1])[c] = (_Float16)hreg;
      zout[(size_t)s * HID + c] = hreg;
    }
    __syncthreads();
    xr0 = xr1; xz0 = xz1; xn0 = xn1;
  }
}

// ---------------------------------------------------------------------------
// Phase C: NCE loss + accuracy. One block per t, 4 waves = 4 timespans.
// Reads f32 z straight from d_out.
// ---------------------------------------------------------------------------
__global__ __launch_bounds__(256) void cpc_kernel(
    const float* __restrict__ x, const float* __restrict__ zf,
    const float* __restrict__ rn, float* __restrict__ accum)
{
  __shared__ float zsh[HID];
  __shared__ float wsum[4];
  __shared__ float nce_s[4], acc_s[4];
  const int tt = TSTART + blockIdx.x;
  const int i = threadIdx.x;
  const int wave = i >> 6, lane = i & 63;

  float zi = zf[(size_t)tt * HID + i];
  zsh[i] = zi;
  float p = zi * zi;
#pragma unroll
  for (int off = 32; off; off >>= 1) p += __shfl_xor(p, off, 64);
  if (lane == 0) wsum[wave] = p;
  __syncthreads();
  float zn = fmaxf(sqrtf(wsum[0] + wsum[1] + wsum[2] + wsum[3]), 1e-8f);

  float z0 = zsh[lane], z1 = zsh[lane + 64], z2 = zsh[lane + 128], z3 = zsh[lane + 192];
  const int base = tt + wave + 1;   // pos index for timespan (wave+1)

  float tot[10];
#pragma unroll
  for (int n = 0; n < 10; ++n) {
    int idx = base + (n > 0 ? (NEGD + n - 1) : 0);
    const float* xr = x + (size_t)idx * HID;
    float q = xr[lane] * z0 + xr[lane + 64] * z1 + xr[lane + 128] * z2 + xr[lane + 192] * z3;
#pragma unroll
    for (int off = 32; off; off >>= 1) q += __shfl_xor(q, off, 64);
    tot[n] = q / (rn[idx] * zn);
  }
  float m = tot[0];
#pragma unroll
  for (int n = 1; n < 10; ++n) m = fmaxf(m, tot[n]);
  float se = 0.f;
#pragma unroll
  for (int n = 0; n < 10; ++n) se += expf(tot[n] - m);
  float logp0 = (tot[0] - m) - logf(se);
  float accv = (tot[0] >= m) ? 1.0f : 0.0f;  // argmax==0 iff tot[0] is the max

  if (lane == 0) { nce_s[wave] = -logp0; acc_s[wave] = accv; }
  __syncthreads();
  if (i == 0) {
    atomicAdd(accum,     nce_s[0] + nce_s[1] + nce_s[2] + nce_s[3]);
    atomicAdd(accum + 1, acc_s[0] + acc_s[1] + acc_s[2] + acc_s[3]);
  }
}

__global__ void fin_kernel(const float* __restrict__ accum,
                           float* __restrict__ out)
{
  if (threadIdx.x == 0) {
    out[(size_t)SEQ * HID]     = accum[0] / DENOMF;   // nce
    out[(size_t)SEQ * HID + 1] = accum[1] / DENOMF;   // acc
  }
}

// ---------------------------------------------------------------------------
extern "C" void kernel_launch(void* const* d_in, const int* in_sizes, int n_in,
                              void* d_out, int out_size, void* d_ws, size_t ws_size,
                              hipStream_t stream)
{
  // Inputs are f32 (reference dtypes). Output f32: z [SEQ*HID] | nce | acc.
  const float* data = (const float*)d_in[0];
  const float* Wih  = (const float*)d_in[1];
  const float* Whh  = (const float*)d_in[2];
  const float* bih  = (const float*)d_in[3];
  const float* bhh  = (const float*)d_in[4];
  float* out = (float*)d_out;

  // ws layout: xw f32 [SEQ*768] 25.17MB | rn f32 [SEQ] | accum f32 [2]
  char* p = (char*)d_ws;
  float* xw    = (float*)p;  p += (size_t)SEQ * G3 * sizeof(float);
  float* rn    = (float*)p;  p += (size_t)SEQ * sizeof(float);
  float* accum = (float*)p;

  init_kernel<<<1, 64, 0, stream>>>(accum);
  xw_kernel<<<dim3(256, 3), 256, 0, stream>>>(data, Wih, bih, xw);
  rnorm_kernel<<<SEQ / 4, 256, 0, stream>>>(data, rn);
  gru_kernel<<<1, 512, 0, stream>>>(Whh, bhh, xw, out);
  cpc_kernel<<<TCNT, 256, 0, stream>>>(data, out, rn, accum);
  fin_kernel<<<1, 1, 0, stream>>>(accum, out);
}